// Round 1
// baseline (356.826 us; speedup 1.0000x reference)
//
#include <hip/hip_runtime.h>

typedef __attribute__((ext_vector_type(8))) short s8v;   // 8 bf16 vals
typedef __attribute__((ext_vector_type(4))) float f4v;   // MFMA C/D

#define B_ 4
#define S_ 4096
#define E_ 1024
#define D_ 128

__device__ __forceinline__ unsigned short f2bf(float f) {
  unsigned int u = __float_as_uint(f);
  return (unsigned short)((u + 0x7FFFu + ((u >> 16) & 1u)) >> 16);
}

// ---------------- projection: out = x @ W  (M=16384, K=1024, N=128) --------
// proj 0: Q row-major [16384][128] bf16
// proj 1: K row-major [16384][128] bf16
// proj 2: V transposed [b][128][4096] bf16
__global__ __launch_bounds__(256) void proj_kernel(
    const float* __restrict__ x,
    const float* __restrict__ Wq, const float* __restrict__ Wk,
    const float* __restrict__ Wv,
    unsigned short* __restrict__ Qb, unsigned short* __restrict__ Kb,
    unsigned short* __restrict__ VT) {
  __shared__ __align__(16) unsigned short Blds[128 * 72];  // [n][64k + 8 pad]
  const int proj = blockIdx.y;
  const float* W = (proj == 0) ? Wq : (proj == 1) ? Wk : Wv;
  unsigned short* out = (proj == 0) ? Qb : (proj == 1) ? Kb : VT;

  const int m0 = blockIdx.x * 64;
  const int t = threadIdx.x;
  const int wv = t >> 6, lane = t & 63, quad = lane >> 4, l16 = lane & 15;

  f4v acc[8];
  const f4v fzero = {0.f, 0.f, 0.f, 0.f};
#pragma unroll
  for (int i = 0; i < 8; ++i) acc[i] = fzero;

  const int kS = t & 63;         // staging local-k (0..63)
  const int n0 = (t >> 6) * 32;  // staging n base

  for (int kk = 0; kk < E_; kk += 64) {
    __syncthreads();
    // stage W[kk+k][n] -> Blds[n][k] (transposed, bf16)
    const float* wp = W + (size_t)(kk + kS) * D_ + n0;
#pragma unroll
    for (int j = 0; j < 32; j += 4) {
      float4 w4 = *reinterpret_cast<const float4*>(wp + j);
      Blds[(n0 + j + 0) * 72 + kS] = f2bf(w4.x);
      Blds[(n0 + j + 1) * 72 + kS] = f2bf(w4.y);
      Blds[(n0 + j + 2) * 72 + kS] = f2bf(w4.z);
      Blds[(n0 + j + 3) * 72 + kS] = f2bf(w4.w);
    }
    __syncthreads();
    const float* xp = x + (size_t)(m0 + wv * 16 + l16) * E_ + kk + quad * 8;
#pragma unroll
    for (int ks = 0; ks < 2; ++ks) {
      float4 a0 = *reinterpret_cast<const float4*>(xp + ks * 32);
      float4 a1 = *reinterpret_cast<const float4*>(xp + ks * 32 + 4);
      s8v af;
      af[0] = (short)f2bf(a0.x); af[1] = (short)f2bf(a0.y);
      af[2] = (short)f2bf(a0.z); af[3] = (short)f2bf(a0.w);
      af[4] = (short)f2bf(a1.x); af[5] = (short)f2bf(a1.y);
      af[6] = (short)f2bf(a1.z); af[7] = (short)f2bf(a1.w);
#pragma unroll
      for (int nt = 0; nt < 8; ++nt) {
        s8v bf = *reinterpret_cast<const s8v*>(
            &Blds[(nt * 16 + l16) * 72 + ks * 32 + quad * 8]);
        acc[nt] = __builtin_amdgcn_mfma_f32_16x16x32_bf16(af, bf, acc[nt], 0, 0, 0);
      }
    }
  }
  // epilogue: C/D layout row=quad*4+reg, col=lane&15 (+16*nt)
#pragma unroll
  for (int nt = 0; nt < 8; ++nt) {
#pragma unroll
    for (int r = 0; r < 4; ++r) {
      int row = m0 + wv * 16 + quad * 4 + r;
      int col = nt * 16 + l16;
      unsigned short v = f2bf(acc[nt][r]);
      if (proj == 2)
        out[((size_t)(row >> 12) * D_ + col) * S_ + (row & (S_ - 1))] = v;
      else
        out[(size_t)row * D_ + col] = v;
    }
  }
}

// ---------------- flash attention, causal, barrier-free main loop ----------
// block: 256 thr = 4 waves; each block: one 16-row q tile of one batch;
// waves split the key range (32-key blocks, round robin), combined at end.
__global__ __launch_bounds__(256) void flash_kernel(
    const unsigned short* __restrict__ Qb,
    const unsigned short* __restrict__ Kb,
    const unsigned short* __restrict__ VT,
    float* __restrict__ out) {
  __shared__ __align__(16) float smem[4 * 2048 + 128];  // Ow[4][16][128] | m[4][16] | l[4][16]
  const int qt = blockIdx.x;
  const int b = blockIdx.y;
  const int q0 = qt * 16;
  const int t = threadIdx.x;
  const int wv = t >> 6, lane = t & 63, quad = lane >> 4, l16 = lane & 15;

  const float SCL = 0.03125f * 1.44269504088896340736f;  // (1/sqrt(1024))*log2(e)

  // Q A-frags, held in registers for whole loop
  s8v Qf[4];
  const unsigned short* qp = Qb + ((size_t)b * S_ + q0 + l16) * D_ + quad * 8;
#pragma unroll
  for (int ks = 0; ks < 4; ++ks)
    Qf[ks] = *reinterpret_cast<const s8v*>(qp + ks * 32);

  f4v O[8];
  const f4v fzero = {0.f, 0.f, 0.f, 0.f};
#pragma unroll
  for (int i = 0; i < 8; ++i) O[i] = fzero;
  float m_r[4], l_r[4];
#pragma unroll
  for (int r = 0; r < 4; ++r) { m_r[r] = -3.0e38f; l_r[r] = 0.f; }

  // per-wave P buffer aliases the start of this wave's Ow region (used disjointly in time)
  unsigned short* pbuf = reinterpret_cast<unsigned short*>(&smem[wv * 2048]);

  const int nkb = (q0 + 47) >> 5;  // # of 32-key blocks covering keys 0..q0+15
  for (int kb = wv; kb < nkb; kb += 4) {
    const int k0 = kb * 32;
    // ---- S = Q K^T (16q x 32k) ----
    f4v Sa[2];
    Sa[0] = fzero; Sa[1] = fzero;
#pragma unroll
    for (int ks = 0; ks < 4; ++ks) {
#pragma unroll
      for (int nt = 0; nt < 2; ++nt) {
        const unsigned short* kp =
            Kb + ((size_t)b * S_ + k0 + nt * 16 + l16) * D_ + ks * 32 + quad * 8;
        s8v kf = *reinterpret_cast<const s8v*>(kp);
        Sa[nt] = __builtin_amdgcn_mfma_f32_16x16x32_bf16(Qf[ks], kf, Sa[nt], 0, 0, 0);
      }
    }
    // ---- mask + scale, row max ----
    float p[2][4], mx[4];
#pragma unroll
    for (int r = 0; r < 4; ++r) {
      int row = q0 + quad * 4 + r;
#pragma unroll
      for (int nt = 0; nt < 2; ++nt) {
        int col = k0 + nt * 16 + l16;
        float v = Sa[nt][r] * SCL;
        p[nt][r] = (col > row) ? -3.0e38f : v;
      }
      mx[r] = fmaxf(p[0][r], p[1][r]);
    }
#pragma unroll
    for (int d = 1; d < 16; d <<= 1)
#pragma unroll
      for (int r = 0; r < 4; ++r) mx[r] = fmaxf(mx[r], __shfl_xor(mx[r], d));
    // ---- online softmax update ----
    float alpha[4], rs[4];
#pragma unroll
    for (int r = 0; r < 4; ++r) {
      float mn = fmaxf(m_r[r], mx[r]);
      alpha[r] = exp2f(m_r[r] - mn);
      m_r[r] = mn;
      float p0 = exp2f(p[0][r] - mn);
      float p1 = exp2f(p[1][r] - mn);
      rs[r] = p0 + p1;
      pbuf[(quad * 4 + r) * 32 + l16] = f2bf(p0);
      pbuf[(quad * 4 + r) * 32 + 16 + l16] = f2bf(p1);
    }
#pragma unroll
    for (int d = 1; d < 16; d <<= 1)
#pragma unroll
      for (int r = 0; r < 4; ++r) rs[r] += __shfl_xor(rs[r], d);
#pragma unroll
    for (int r = 0; r < 4; ++r) l_r[r] = l_r[r] * alpha[r] + rs[r];
#pragma unroll
    for (int nt = 0; nt < 8; ++nt)
#pragma unroll
      for (int r = 0; r < 4; ++r) O[nt][r] *= alpha[r];
    // ---- P (C-layout) -> A-layout via LDS round trip ----
    s8v Pf = *reinterpret_cast<const s8v*>(&pbuf[l16 * 32 + quad * 8]);
    // ---- O += P V ----
#pragma unroll
    for (int nt = 0; nt < 8; ++nt) {
      const unsigned short* vp =
          VT + ((size_t)b * D_ + nt * 16 + l16) * S_ + k0 + quad * 8;
      s8v vf = *reinterpret_cast<const s8v*>(vp);
      O[nt] = __builtin_amdgcn_mfma_f32_16x16x32_bf16(Pf, vf, O[nt], 0, 0, 0);
    }
  }

  // ---- per-wave results to LDS ----
  float* Ow = &smem[wv * 2048];
#pragma unroll
  for (int nt = 0; nt < 8; ++nt)
#pragma unroll
    for (int r = 0; r < 4; ++r)
      Ow[(quad * 4 + r) * 128 + nt * 16 + l16] = O[nt][r];
  if (l16 == 0) {
#pragma unroll
    for (int r = 0; r < 4; ++r) {
      smem[8192 + wv * 16 + quad * 4 + r] = m_r[r];
      smem[8192 + 64 + wv * 16 + quad * 4 + r] = l_r[r];
    }
  }
  __syncthreads();
  // ---- combine 4 waves' (m,l,O), divide by l, write out ----
  const int col = t & 127;
  const int half = t >> 7;
#pragma unroll
  for (int i = 0; i < 8; ++i) {
    int r = half * 8 + i;
    float mstar = -3.0e38f;
#pragma unroll
    for (int w = 0; w < 4; ++w) mstar = fmaxf(mstar, smem[8192 + w * 16 + r]);
    float Lsum = 0.f, Osum = 0.f;
#pragma unroll
    for (int w = 0; w < 4; ++w) {
      float sc = exp2f(smem[8192 + w * 16 + r] - mstar);
      Lsum += sc * smem[8192 + 64 + w * 16 + r];
      Osum += sc * smem[w * 2048 + r * 128 + col];
    }
    out[((size_t)b * S_ + q0 + r) * D_ + col] = Osum / Lsum;
  }
}

extern "C" void kernel_launch(void* const* d_in, const int* in_sizes, int n_in,
                              void* d_out, int out_size, void* d_ws, size_t ws_size,
                              hipStream_t stream) {
  const float* x = (const float*)d_in[0];
  const float* Wq = (const float*)d_in[1];
  const float* Wk = (const float*)d_in[2];
  const float* Wv = (const float*)d_in[3];
  float* out = (float*)d_out;

  unsigned short* Qb = (unsigned short*)d_ws;                  // [16384][128] bf16
  unsigned short* Kb = Qb + (size_t)16384 * 128;               // [16384][128] bf16
  unsigned short* VT = Kb + (size_t)16384 * 128;               // [4][128][4096] bf16

  proj_kernel<<<dim3(256, 3), 256, 0, stream>>>(x, Wq, Wk, Wv, Qb, Kb, VT);
  flash_kernel<<<dim3(256, 4), 256, 0, stream>>>(Qb, Kb, VT, out);
}